// Round 7
// baseline (353.894 us; speedup 1.0000x reference)
//
#include <hip/hip_runtime.h>
#include <hip/hip_bf16.h>

#define NUM_HEADS   32
#define NUM_KV_HEADS 8
#define HEAD_DIM    128
#define GQA          4
#define Q_LEN      256
#define MAX_PAGES  128
#define PAGE_SIZE   16
#define SCALE 0.08838834764831845f
#define LOG2E 1.44269504088896340736f
#define RESCALE_THR 8.0f

// 32-token chunks
#define NCH_MAX   72                      // ceil((2047+256)/32)
#define CHUNK_B   8192                    // 32 tokens * 128 d * 2B
#define KSTREAM   ((size_t)NCH_MAX * CHUNK_B)   // 589824 B per (b,kvh) stream
#define NITEMS    512
#define PFLOATS   16640                   // per-partial: 16384 O + 256 ml (floats)

typedef __bf16 bf16x8 __attribute__((ext_vector_type(8)));
typedef float  f32x4  __attribute__((ext_vector_type(4)));

union B8 { uint4 u; bf16x8 v; };

__device__ __forceinline__ unsigned f2bf(float x){
    unsigned u = __builtin_bit_cast(unsigned, x);
    return (u + 0x7fffu + ((u >> 16) & 1u)) >> 16;
}
__device__ __forceinline__ unsigned pack2(float lo, float hi){
    return f2bf(lo) | (f2bf(hi) << 16);
}

typedef __attribute__((address_space(3))) unsigned char lds_as3_t;
typedef const __attribute__((address_space(1))) void gas_v;
typedef __attribute__((address_space(3))) void las_v;

#define GLD16(g, l) __builtin_amdgcn_global_load_lds((gas_v*)(g), (las_v*)(l), 16, 0, 0)

#define TRR(dst, base, OFF) asm volatile("ds_read_b64_tr_b16 %0, %1 offset:" OFF \
                                         : "=v"(dst) : "v"(base))

// ============================ pre-pass: gather + bf16 + pre-swizzle ============================
// K image per 32-t chunk: byte = t*256 + ((d*2) ^ ((t&7)<<4))            (32 x 256B = 8KB)
// V image per 32-t chunk: byte = (d>>4)*1024 + (t>>2)*128 + (t&3)*32 + (d&15)*2
__global__ __launch_bounds__(256) void prep_kernel(
    const float* __restrict__ knew,
    const float* __restrict__ vnew,
    const float* __restrict__ kcache,
    const float* __restrict__ vcache,
    const int*   __restrict__ ptab,
    const int*   __restrict__ ctxlens,
    unsigned char* __restrict__ kimg,
    unsigned char* __restrict__ vimg)
{
    const int ch  = blockIdx.x;
    const int kvh = blockIdx.y;
    const int b   = blockIdx.z;
    const int ctxlen = ctxlens[b];
    const int lim = ctxlen + Q_LEN;
    const int base = ch * 32;
    if (base >= lim) return;

    const int tid  = threadIdx.x;
    const int srow = tid >> 3;        // 0..31 token within chunk
    const int seg  = tid & 7;         // 16-float segment of d
    const int t    = base + srow;

    unsigned char* kdst = kimg + (size_t)(b * 8 + kvh) * KSTREAM + (size_t)ch * CHUNK_B;
    unsigned char* vdst = vimg + (size_t)(b * 8 + kvh) * KSTREAM + (size_t)ch * CHUNK_B;
    const int swz    = (srow & 7) << 4;
    const int vbyte0 = seg * 1024 + (srow >> 2) * 128 + (srow & 3) * 32;

    if (t < lim){
        size_t roff;
        const float *ksrc, *vsrc;
        if (t < ctxlen){
            const int page = ptab[b * MAX_PAGES + (t >> 4)];
            roff = ((size_t)(page * PAGE_SIZE + (t & 15)) * NUM_KV_HEADS + kvh) * HEAD_DIM;
            ksrc = kcache + roff; vsrc = vcache + roff;
        } else {
            roff = ((size_t)(b * Q_LEN + (t - ctxlen)) * NUM_KV_HEADS + kvh) * HEAD_DIM;
            ksrc = knew + roff; vsrc = vnew + roff;
        }
        const float* kr = ksrc + seg * 16;
        const float* vr = vsrc + seg * 16;
        #pragma unroll
        for (int i = 0; i < 2; ++i){
            float4 a  = *(const float4*)(kr + i * 8);
            float4 c4 = *(const float4*)(kr + i * 8 + 4);
            uint4 wv;
            wv.x = pack2(a.x, a.y);  wv.y = pack2(a.z, a.w);
            wv.z = pack2(c4.x, c4.y); wv.w = pack2(c4.z, c4.w);
            *(uint4*)(kdst + srow * 256 + ((seg * 32 + i * 16) ^ swz)) = wv;
        }
        {
            const float4 a0 = *(const float4*)(vr + 0);
            const float4 a1 = *(const float4*)(vr + 4);
            const float4 a2 = *(const float4*)(vr + 8);
            const float4 a3 = *(const float4*)(vr + 12);
            uint4 w0, w1;
            w0.x = pack2(a0.x, a0.y); w0.y = pack2(a0.z, a0.w);
            w0.z = pack2(a1.x, a1.y); w0.w = pack2(a1.z, a1.w);
            w1.x = pack2(a2.x, a2.y); w1.y = pack2(a2.z, a2.w);
            w1.z = pack2(a3.x, a3.y); w1.w = pack2(a3.z, a3.w);
            *(uint4*)(vdst + vbyte0)      = w0;
            *(uint4*)(vdst + vbyte0 + 16) = w1;
        }
    } else {
        const uint4 z = {0u, 0u, 0u, 0u};
        #pragma unroll
        for (int i = 0; i < 2; ++i)
            *(uint4*)(kdst + srow * 256 + ((seg * 32 + i * 16) ^ swz)) = z;
        *(uint4*)(vdst + vbyte0)      = z;
        *(uint4*)(vdst + vbyte0 + 16) = z;
    }
}

// ============================ attention kernel (context-split) ============================
// LDS 32KB: K dbuf [2][8KB] at 0, V dbuf [2][8KB] at 16384 -> 4-5 blocks/CU.
template<int NSPLIT>
__global__ __launch_bounds__(256, 4) void attn_kernel(
    const float* __restrict__ q,
    const int*   __restrict__ ctxlens,
    float*       __restrict__ out,
    const unsigned char* __restrict__ kimg,
    const unsigned char* __restrict__ vimg,
    float* __restrict__ part)
{
    __shared__ __align__(16) unsigned char lds[32768];

    const int tid  = threadIdx.x;
    const int w    = tid >> 6;
    const int lane = tid & 63;
    const int hh   = lane >> 4;
    const int cq   = lane & 15;

    const unsigned ldsb3 = (unsigned)(unsigned long long)(lds_as3_t*)(&lds[0]);

    const int fid  = blockIdx.x;
    const int item = (NITEMS - 1) - (fid / NSPLIT);   // long items (s32=7) dispatch first
    const int seg  = fid % NSPLIT;

    const int b   = item & 7;
    const int kvh = (item >> 3) & 7;
    const int s32 = item >> 6;

    const int s0 = s32 * 32;
    const int ctxlen = ctxlens[b];
    const int vlim = ctxlen + (s32 + 1) * 32;
    const int nch  = (vlim + 31) >> 5;
    const int lo   = (seg * nch) / NSPLIT;
    const int hi   = ((seg + 1) * nch) / NSPLIT;
    if (lo >= hi) return;                  // empty split (uniform per block)
    const int hq = kvh * GQA + w;

    const unsigned char* kstream = kimg + (size_t)(b * 8 + kvh) * KSTREAM;
    const unsigned char* vstream = vimg + (size_t)(b * 8 + kvh) * KSTREAM;

    #define STAGE(CH, PB) do { \
        const unsigned char* kg_ = kstream + (size_t)(CH) * CHUNK_B + (w * 1024 + lane * 16); \
        const unsigned char* vg_ = vstream + (size_t)(CH) * CHUNK_B + (w * 1024 + lane * 16); \
        GLD16(kg_,        lds + (PB) * 8192 + w * 1024); \
        GLD16(kg_ + 4096, lds + (PB) * 8192 + w * 1024 + 4096); \
        GLD16(vg_,        lds + 16384 + (PB) * 8192 + w * 1024); \
        GLD16(vg_ + 4096, lds + 16384 + (PB) * 8192 + w * 1024 + 4096); \
    } while (0)

    STAGE(lo, lo & 1);

    // Q fragments (B-operand), two 16-row tiles, pre-scaled into log2 domain
    B8 qf[2][4];
    #pragma unroll
    for (int u = 0; u < 2; ++u){
        const float* qrow = q + (size_t)(b * Q_LEN + s0 + u * 16 + cq) * (NUM_HEADS * HEAD_DIM)
                              + hq * HEAD_DIM;
        #pragma unroll
        for (int c = 0; c < 4; ++c){
            const float4 f0 = *(const float4*)(qrow + c * 32 + 8 * hh);
            const float4 f1 = *(const float4*)(qrow + c * 32 + 8 * hh + 4);
            const float sc = SCALE * LOG2E;
            qf[u][c].u.x = pack2(f0.x * sc, f0.y * sc);
            qf[u][c].u.y = pack2(f0.z * sc, f0.w * sc);
            qf[u][c].u.z = pack2(f1.x * sc, f1.y * sc);
            qf[u][c].u.w = pack2(f1.z * sc, f1.w * sc);
        }
    }

    f32x4 acc[2][8] = {};
    float mrun[2] = {-1e30f, -1e30f};
    float lp[2]   = {0.f, 0.f};

    __syncthreads();   // buffer (lo&1) ready (implicit vmcnt(0) drain)

    for (int ch = lo; ch < hi; ++ch){
        const int pb = ch & 1;
        if (ch + 1 < hi) STAGE(ch + 1, pb ^ 1);   // depth-1 prefetch under compute

        const int base = ch * 32;
        const unsigned kb = (unsigned)(pb * 8192);

        // ---------------- QK^T (swapped): st[u][tf] = S^T[t][q] ----------------
        __builtin_amdgcn_s_setprio(1);
        f32x4 st[2][2] = {};
        #pragma unroll
        for (int c = 0; c < 4; ++c){
            #pragma unroll
            for (int tf = 0; tf < 2; ++tf){
                const int trow = tf * 16 + cq;
                const unsigned byte = kb + trow * 256 + ((c * 64 + hh * 16) ^ ((trow & 7) << 4));
                B8 kf; kf.u = *(const uint4*)(lds + byte);
                st[0][tf] = __builtin_amdgcn_mfma_f32_16x16x32_bf16(kf.v, qf[0][c].v, st[0][tf], 0, 0, 0);
                st[1][tf] = __builtin_amdgcn_mfma_f32_16x16x32_bf16(kf.v, qf[1][c].v, st[1][tf], 0, 0, 0);
            }
        }
        __builtin_amdgcn_s_setprio(0);

        // ---------------- softmax (defer-max + deferred-l, base-2) ----------------
        B8 af[2];
        const bool interior = (base + 32 <= vlim);
        #pragma unroll
        for (int u = 0; u < 2; ++u){
            float p[2][4];
            float pm = -1e30f;
            if (interior){
                #pragma unroll
                for (int tf = 0; tf < 2; ++tf){
                    #pragma unroll
                    for (int r = 0; r < 4; ++r){
                        const float s = st[u][tf][r];
                        p[tf][r] = s;
                        pm = fmaxf(pm, s);
                    }
                }
            } else {
                #pragma unroll
                for (int tf = 0; tf < 2; ++tf){
                    #pragma unroll
                    for (int r = 0; r < 4; ++r){
                        const int t = base + tf * 16 + hh * 4 + r;
                        const float s = (t < vlim) ? st[u][tf][r] : -1e30f;
                        p[tf][r] = s;
                        pm = fmaxf(pm, s);
                    }
                }
            }
            pm = fmaxf(pm, __shfl_xor(pm, 16));
            pm = fmaxf(pm, __shfl_xor(pm, 32));

            if (!__all(pm <= mrun[u] + RESCALE_THR)){
                const float mnew  = fmaxf(mrun[u], pm);
                const float alpha = __builtin_amdgcn_exp2f(mrun[u] - mnew);
                mrun[u] = mnew;
                lp[u] *= alpha;
                float a4[4];
                #pragma unroll
                for (int r = 0; r < 4; ++r) a4[r] = __shfl(alpha, hh * 20 + r);
                #pragma unroll
                for (int dc = 0; dc < 8; ++dc){
                    #pragma unroll
                    for (int r = 0; r < 4; ++r) acc[u][dc][r] *= a4[r];
                }
            }
            const float m = mrun[u];
            float rsum = 0.f;
            #pragma unroll
            for (int tf = 0; tf < 2; ++tf){
                #pragma unroll
                for (int r = 0; r < 4; ++r){
                    const float e = __builtin_amdgcn_exp2f(p[tf][r] - m);
                    p[tf][r] = e;
                    rsum += e;
                }
            }
            lp[u] += rsum;

            // k-axis mapping: t(8hh+j) = 16*(j>>2) + 4hh + (j&3)
            af[u].u.x = pack2(p[0][0], p[0][1]);
            af[u].u.y = pack2(p[0][2], p[0][3]);
            af[u].u.z = pack2(p[1][0], p[1][1]);
            af[u].u.w = pack2(p[1][2], p[1][3]);
        }

        // ---------------- PV via hardware transpose reads; vf shared by tiles ----------------
        {
            const unsigned trb = ldsb3 + 16384u + (unsigned)(pb * 8192)
                               + (unsigned)(hh * 128 + cq * 8);
            unsigned long long r0,r1,r2,r3,r4,r5,r6,r7;
            B8 vf;
            __builtin_amdgcn_s_setprio(1);
            // ---- dc=0..3 ----
            TRR(r0, trb, "0");     TRR(r1, trb, "512");
            TRR(r2, trb, "1024");  TRR(r3, trb, "1536");
            TRR(r4, trb, "2048");  TRR(r5, trb, "2560");
            TRR(r6, trb, "3072");  TRR(r7, trb, "3584");
            asm volatile("s_waitcnt lgkmcnt(0)" ::: "memory");
            __builtin_amdgcn_sched_barrier(0);
            vf.u.x=(unsigned)r0; vf.u.y=(unsigned)(r0>>32); vf.u.z=(unsigned)r1; vf.u.w=(unsigned)(r1>>32);
            acc[0][0] = __builtin_amdgcn_mfma_f32_16x16x32_bf16(af[0].v, vf.v, acc[0][0], 0, 0, 0);
            acc[1][0] = __builtin_amdgcn_mfma_f32_16x16x32_bf16(af[1].v, vf.v, acc[1][0], 0, 0, 0);
            vf.u.x=(unsigned)r2; vf.u.y=(unsigned)(r2>>32); vf.u.z=(unsigned)r3; vf.u.w=(unsigned)(r3>>32);
            acc[0][1] = __builtin_amdgcn_mfma_f32_16x16x32_bf16(af[0].v, vf.v, acc[0][1], 0, 0, 0);
            acc[1][1] = __builtin_amdgcn_mfma_f32_16x16x32_bf16(af[1].v, vf.v, acc[1][1], 0, 0, 0);
            vf.u.x=(unsigned)r4; vf.u.y=(unsigned)(r4>>32); vf.u.z=(unsigned)r5; vf.u.w=(unsigned)(r5>>32);
            acc[0][2] = __builtin_amdgcn_mfma_f32_16x16x32_bf16(af[0].v, vf.v, acc[0][2], 0, 0, 0);
            acc[1][2] = __builtin_amdgcn_mfma_f32_16x16x32_bf16(af[1].v, vf.v, acc[1][2], 0, 0, 0);
            vf.u.x=(unsigned)r6; vf.u.y=(unsigned)(r6>>32); vf.u.z=(unsigned)r7; vf.u.w=(unsigned)(r7>>32);
            acc[0][3] = __builtin_amdgcn_mfma_f32_16x16x32_bf16(af[0].v, vf.v, acc[0][3], 0, 0, 0);
            acc[1][3] = __builtin_amdgcn_mfma_f32_16x16x32_bf16(af[1].v, vf.v, acc[1][3], 0, 0, 0);
            // ---- dc=4..7 ----
            TRR(r0, trb, "4096");  TRR(r1, trb, "4608");
            TRR(r2, trb, "5120");  TRR(r3, trb, "5632");
            TRR(r4, trb, "6144");  TRR(r5, trb, "6656");
            TRR(r6, trb, "7168");  TRR(r7, trb, "7680");
            asm volatile("s_waitcnt lgkmcnt(0)" ::: "memory");
            __builtin_amdgcn_sched_barrier(0);
            vf.u.x=(unsigned)r0; vf.u.y=(unsigned)(r0>>32); vf.u.z=(unsigned)r1; vf.u.w=(unsigned)(r1>>32);
            acc[0][4] = __builtin_amdgcn_mfma_f32_16x16x32_bf16(af[0].v, vf.v, acc[0][4], 0, 0, 0);
            acc[1][4] = __builtin_amdgcn_mfma_f32_16x16x32_bf16(af[1].v, vf.v, acc[1][4], 0, 0, 0);
            vf.u.x=(unsigned)r2; vf.u.y=(unsigned)(r2>>32); vf.u.z=(unsigned)r3; vf.u.w=(unsigned)(r3>>32);
            acc[0][5] = __builtin_amdgcn_mfma_f32_16x16x32_bf16(af[0].v, vf.v, acc[0][5], 0, 0, 0);
            acc[1][5] = __builtin_amdgcn_mfma_f32_16x16x32_bf16(af[1].v, vf.v, acc[1][5], 0, 0, 0);
            vf.u.x=(unsigned)r4; vf.u.y=(unsigned)(r4>>32); vf.u.z=(unsigned)r5; vf.u.w=(unsigned)(r5>>32);
            acc[0][6] = __builtin_amdgcn_mfma_f32_16x16x32_bf16(af[0].v, vf.v, acc[0][6], 0, 0, 0);
            acc[1][6] = __builtin_amdgcn_mfma_f32_16x16x32_bf16(af[1].v, vf.v, acc[1][6], 0, 0, 0);
            vf.u.x=(unsigned)r6; vf.u.y=(unsigned)(r6>>32); vf.u.z=(unsigned)r7; vf.u.w=(unsigned)(r7>>32);
            acc[0][7] = __builtin_amdgcn_mfma_f32_16x16x32_bf16(af[0].v, vf.v, acc[0][7], 0, 0, 0);
            acc[1][7] = __builtin_amdgcn_mfma_f32_16x16x32_bf16(af[1].v, vf.v, acc[1][7], 0, 0, 0);
            __builtin_amdgcn_s_setprio(0);
        }
        __syncthreads();   // drains prefetch DMA; separates buf reads from next overwrite
    }

    // ---------------- epilogue ----------------
    if (NSPLIT == 1){
        #pragma unroll
        for (int u = 0; u < 2; ++u){
            float l = lp[u];
            l += __shfl_xor(l, 16);
            l += __shfl_xor(l, 32);
            const float li = 1.0f / l;
            float li4[4];
            #pragma unroll
            for (int r = 0; r < 4; ++r) li4[r] = __shfl(li, hh * 20 + r);
            #pragma unroll
            for (int dc = 0; dc < 8; ++dc){
                #pragma unroll
                for (int r = 0; r < 4; ++r){
                    const int so = s0 + u * 16 + hh * 4 + r;
                    out[(size_t)(b * Q_LEN + so) * (NUM_HEADS * HEAD_DIM) + hq * HEAD_DIM + dc * 16 + cq]
                        = acc[u][dc][r] * li4[r];
                }
            }
        }
    } else {
        float* pp = part + (size_t)fid * PFLOATS;
        #pragma unroll
        for (int u = 0; u < 2; ++u){
            float l = lp[u];
            l += __shfl_xor(l, 16);
            l += __shfl_xor(l, 32);
            if (hh == 0){
                pp[16384 + (w * 32 + u * 16 + cq) * 2 + 0] = mrun[u];
                pp[16384 + (w * 32 + u * 16 + cq) * 2 + 1] = l;
            }
            #pragma unroll
            for (int dc = 0; dc < 8; ++dc){
                #pragma unroll
                for (int r = 0; r < 4; ++r){
                    pp[(w * 32 + u * 16 + hh * 4 + r) * 128 + dc * 16 + cq] = acc[u][dc][r];
                }
            }
        }
    }
    #undef STAGE
}

// ============================ merge kernel ============================
template<int NSPLIT>
__global__ __launch_bounds__(256) void merge_kernel(
    const int* __restrict__ ctxlens,
    const float* __restrict__ part,
    float* __restrict__ out)
{
    const int item0 = blockIdx.x;
    const int item = (NITEMS - 1) - item0;            // same remap as attn (fid = item0*NSPLIT+s)
    const int b   = item & 7;
    const int kvh = (item >> 3) & 7;
    const int s32 = item >> 6;
    const int vlim = ctxlens[b] + (s32 + 1) * 32;
    const int nch  = (vlim + 31) >> 5;

    const int tid = threadIdx.x;
    const int h   = tid >> 6;       // head within group
    const int ln  = tid & 63;
    const int row = ln >> 1;        // 0..31
    const int dh  = ln & 1;         // d half (64 floats)

    float m[NSPLIT], l[NSPLIT];
    bool  act[NSPLIT];
    float M = -1e30f;
    #pragma unroll
    for (int s = 0; s < NSPLIT; ++s){
        const int lo = (s * nch) / NSPLIT;
        const int hi = ((s + 1) * nch) / NSPLIT;
        act[s] = hi > lo;
        if (act[s]){
            const float* mlp = part + (size_t)(item0 * NSPLIT + s) * PFLOATS
                             + 16384 + (h * 32 + row) * 2;
            m[s] = mlp[0];
            l[s] = mlp[1];
            M = fmaxf(M, m[s]);
        }
    }
    float L = 0.f;
    float wgt[NSPLIT];
    #pragma unroll
    for (int s = 0; s < NSPLIT; ++s){
        if (act[s]){
            wgt[s] = __builtin_amdgcn_exp2f(m[s] - M);
            L += l[s] * wgt[s];
        } else wgt[s] = 0.f;
    }
    const float inv = 1.0f / L;

    float* orow = out + (size_t)(b * Q_LEN + s32 * 32 + row) * (NUM_HEADS * HEAD_DIM)
                + (kvh * GQA + h) * HEAD_DIM + dh * 64;
    #pragma unroll
    for (int d4 = 0; d4 < 16; ++d4){
        float4 a = {0.f, 0.f, 0.f, 0.f};
        #pragma unroll
        for (int s = 0; s < NSPLIT; ++s){
            if (act[s]){
                const float4 v = *(const float4*)(part + (size_t)(item0 * NSPLIT + s) * PFLOATS
                                                  + (h * 32 + row) * 128 + dh * 64 + d4 * 4);
                a.x += v.x * wgt[s]; a.y += v.y * wgt[s];
                a.z += v.z * wgt[s]; a.w += v.w * wgt[s];
            }
        }
        a.x *= inv; a.y *= inv; a.z *= inv; a.w *= inv;
        *(float4*)(orow + d4 * 4) = a;
    }
}

extern "C" void kernel_launch(void* const* d_in, const int* in_sizes, int n_in,
                              void* d_out, int out_size, void* d_ws, size_t ws_size,
                              hipStream_t stream) {
    const float* q  = (const float*)d_in[0];
    const float* k  = (const float*)d_in[1];
    const float* v  = (const float*)d_in[2];
    const float* kc = (const float*)d_in[3];
    const float* vc = (const float*)d_in[4];
    const int*   pt = (const int*)d_in[5];
    const int*   cl = (const int*)d_in[6];
    float* o = (float*)d_out;

    const size_t img_bytes = (size_t)64 * KSTREAM;            // 37,748,736 per image
    const size_t off_part  = 256 + 2 * img_bytes;             // 75,497,728
    const size_t pb_bytes  = (size_t)PFLOATS * 4;             // 66,560
    const size_t need4 = off_part + (size_t)NITEMS * 4 * pb_bytes;  // ~212 MB
    const size_t need2 = off_part + (size_t)NITEMS * 2 * pb_bytes;  // ~144 MB
    const size_t need1 = off_part;

    unsigned char* kimg = (unsigned char*)d_ws + 256;
    unsigned char* vimg = kimg + img_bytes;
    float* part = (float*)((unsigned char*)d_ws + off_part);

    prep_kernel<<<dim3(NCH_MAX, 8, 8), 256, 0, stream>>>(k, v, kc, vc, pt, cl, kimg, vimg);

    if (ws_size >= need4) {
        attn_kernel<4><<<NITEMS * 4, 256, 0, stream>>>(q, cl, o, kimg, vimg, part);
        merge_kernel<4><<<NITEMS, 256, 0, stream>>>(cl, part, o);
    } else if (ws_size >= need2) {
        attn_kernel<2><<<NITEMS * 2, 256, 0, stream>>>(q, cl, o, kimg, vimg, part);
        merge_kernel<2><<<NITEMS, 256, 0, stream>>>(cl, part, o);
    } else if (ws_size >= need1) {
        attn_kernel<1><<<NITEMS, 256, 0, stream>>>(q, cl, o, kimg, vimg, part);
    }
}

// Round 8
// 182.370 us; speedup vs baseline: 1.9405x; 1.9405x over previous
//
#include <hip/hip_runtime.h>
#include <hip/hip_bf16.h>

#define NUM_HEADS   32
#define NUM_KV_HEADS 8
#define HEAD_DIM    128
#define GQA          4
#define Q_LEN      256
#define MAX_PAGES  128
#define PAGE_SIZE   16
#define SCALE 0.08838834764831845f
#define LOG2E 1.44269504088896340736f
#define RESCALE_THR 8.0f

// 32-token chunks
#define NCH_MAX   72                      // ceil((2047+256)/32)
#define CHUNK_B   8192                    // 32 tokens * 128 d * 2B
#define KSTREAM   ((size_t)NCH_MAX * CHUNK_B)   // 589824 B per (b,kvh) stream
#define NITEMS    512
#define PBYTES    33792                   // 32768 B bf16 O (frag order) + 1024 B ml (128 x float2)

typedef __bf16 bf16x8 __attribute__((ext_vector_type(8)));
typedef float  f32x4  __attribute__((ext_vector_type(4)));

union B8 { uint4 u; bf16x8 v; };

__device__ __forceinline__ unsigned f2bf(float x){
    unsigned u = __builtin_bit_cast(unsigned, x);
    return (u + 0x7fffu + ((u >> 16) & 1u)) >> 16;
}
__device__ __forceinline__ unsigned pack2(float lo, float hi){
    return f2bf(lo) | (f2bf(hi) << 16);
}
__device__ __forceinline__ float bflo(unsigned h){
    return __builtin_bit_cast(float, h << 16);
}
__device__ __forceinline__ float bfhi(unsigned h){
    return __builtin_bit_cast(float, h & 0xffff0000u);
}

typedef __attribute__((address_space(3))) unsigned char lds_as3_t;
typedef const __attribute__((address_space(1))) void gas_v;
typedef __attribute__((address_space(3))) void las_v;

#define GLD16(g, l) __builtin_amdgcn_global_load_lds((gas_v*)(g), (las_v*)(l), 16, 0, 0)

#define TRR(dst, base, OFF) asm volatile("ds_read_b64_tr_b16 %0, %1 offset:" OFF \
                                         : "=v"(dst) : "v"(base))

// ============================ pre-pass: gather + bf16 + pre-swizzle ============================
__global__ __launch_bounds__(256) void prep_kernel(
    const float* __restrict__ knew,
    const float* __restrict__ vnew,
    const float* __restrict__ kcache,
    const float* __restrict__ vcache,
    const int*   __restrict__ ptab,
    const int*   __restrict__ ctxlens,
    unsigned char* __restrict__ kimg,
    unsigned char* __restrict__ vimg)
{
    const int ch  = blockIdx.x;
    const int kvh = blockIdx.y;
    const int b   = blockIdx.z;
    const int ctxlen = ctxlens[b];
    const int lim = ctxlen + Q_LEN;
    const int base = ch * 32;
    if (base >= lim) return;

    const int tid  = threadIdx.x;
    const int srow = tid >> 3;        // 0..31 token within chunk
    const int seg  = tid & 7;         // 16-float segment of d
    const int t    = base + srow;

    unsigned char* kdst = kimg + (size_t)(b * 8 + kvh) * KSTREAM + (size_t)ch * CHUNK_B;
    unsigned char* vdst = vimg + (size_t)(b * 8 + kvh) * KSTREAM + (size_t)ch * CHUNK_B;
    const int swz    = (srow & 7) << 4;
    const int vbyte0 = seg * 1024 + (srow >> 2) * 128 + (srow & 3) * 32;

    if (t < lim){
        size_t roff;
        const float *ksrc, *vsrc;
        if (t < ctxlen){
            const int page = ptab[b * MAX_PAGES + (t >> 4)];
            roff = ((size_t)(page * PAGE_SIZE + (t & 15)) * NUM_KV_HEADS + kvh) * HEAD_DIM;
            ksrc = kcache + roff; vsrc = vcache + roff;
        } else {
            roff = ((size_t)(b * Q_LEN + (t - ctxlen)) * NUM_KV_HEADS + kvh) * HEAD_DIM;
            ksrc = knew + roff; vsrc = vnew + roff;
        }
        const float* kr = ksrc + seg * 16;
        const float* vr = vsrc + seg * 16;
        #pragma unroll
        for (int i = 0; i < 2; ++i){
            float4 a  = *(const float4*)(kr + i * 8);
            float4 c4 = *(const float4*)(kr + i * 8 + 4);
            uint4 wv;
            wv.x = pack2(a.x, a.y);  wv.y = pack2(a.z, a.w);
            wv.z = pack2(c4.x, c4.y); wv.w = pack2(c4.z, c4.w);
            *(uint4*)(kdst + srow * 256 + ((seg * 32 + i * 16) ^ swz)) = wv;
        }
        {
            const float4 a0 = *(const float4*)(vr + 0);
            const float4 a1 = *(const float4*)(vr + 4);
            const float4 a2 = *(const float4*)(vr + 8);
            const float4 a3 = *(const float4*)(vr + 12);
            uint4 w0, w1;
            w0.x = pack2(a0.x, a0.y); w0.y = pack2(a0.z, a0.w);
            w0.z = pack2(a1.x, a1.y); w0.w = pack2(a1.z, a1.w);
            w1.x = pack2(a2.x, a2.y); w1.y = pack2(a2.z, a2.w);
            w1.z = pack2(a3.x, a3.y); w1.w = pack2(a3.z, a3.w);
            *(uint4*)(vdst + vbyte0)      = w0;
            *(uint4*)(vdst + vbyte0 + 16) = w1;
        }
    } else {
        const uint4 z = {0u, 0u, 0u, 0u};
        #pragma unroll
        for (int i = 0; i < 2; ++i)
            *(uint4*)(kdst + srow * 256 + ((seg * 32 + i * 16) ^ swz)) = z;
        *(uint4*)(vdst + vbyte0)      = z;
        *(uint4*)(vdst + vbyte0 + 16) = z;
    }
}

// ============================ attention kernel (context-split) ============================
// LDS 32KB: K dbuf [2][8KB] at 0, V dbuf [2][8KB] at 16384 -> 4 blocks/CU.
template<int NSPLIT>
__global__ __launch_bounds__(256, 4) void attn_kernel(
    const float* __restrict__ q,
    const int*   __restrict__ ctxlens,
    float*       __restrict__ out,
    const unsigned char* __restrict__ kimg,
    const unsigned char* __restrict__ vimg,
    unsigned char* __restrict__ part)
{
    __shared__ __align__(16) unsigned char lds[32768];

    const int tid  = threadIdx.x;
    const int w    = tid >> 6;
    const int lane = tid & 63;
    const int hh   = lane >> 4;
    const int cq   = lane & 15;

    const unsigned ldsb3 = (unsigned)(unsigned long long)(lds_as3_t*)(&lds[0]);

    const int fid  = blockIdx.x;
    const int item = (NITEMS - 1) - (fid / NSPLIT);   // long items (s32=7) dispatch first
    const int seg  = fid % NSPLIT;

    const int b   = item & 7;
    const int kvh = (item >> 3) & 7;
    const int s32 = item >> 6;

    const int s0 = s32 * 32;
    const int ctxlen = ctxlens[b];
    const int vlim = ctxlen + (s32 + 1) * 32;
    const int nch  = (vlim + 31) >> 5;
    const int lo   = (seg * nch) / NSPLIT;
    const int hi   = ((seg + 1) * nch) / NSPLIT;
    if (lo >= hi) return;                  // empty split (uniform per block)
    const int hq = kvh * GQA + w;

    const unsigned char* kstream = kimg + (size_t)(b * 8 + kvh) * KSTREAM;
    const unsigned char* vstream = vimg + (size_t)(b * 8 + kvh) * KSTREAM;

    #define STAGE(CH, PB) do { \
        const unsigned char* kg_ = kstream + (size_t)(CH) * CHUNK_B + (w * 1024 + lane * 16); \
        const unsigned char* vg_ = vstream + (size_t)(CH) * CHUNK_B + (w * 1024 + lane * 16); \
        GLD16(kg_,        lds + (PB) * 8192 + w * 1024); \
        GLD16(kg_ + 4096, lds + (PB) * 8192 + w * 1024 + 4096); \
        GLD16(vg_,        lds + 16384 + (PB) * 8192 + w * 1024); \
        GLD16(vg_ + 4096, lds + 16384 + (PB) * 8192 + w * 1024 + 4096); \
    } while (0)

    STAGE(lo, lo & 1);

    // Q fragments (B-operand), two 16-row tiles, pre-scaled into log2 domain
    B8 qf[2][4];
    #pragma unroll
    for (int u = 0; u < 2; ++u){
        const float* qrow = q + (size_t)(b * Q_LEN + s0 + u * 16 + cq) * (NUM_HEADS * HEAD_DIM)
                              + hq * HEAD_DIM;
        #pragma unroll
        for (int c = 0; c < 4; ++c){
            const float4 f0 = *(const float4*)(qrow + c * 32 + 8 * hh);
            const float4 f1 = *(const float4*)(qrow + c * 32 + 8 * hh + 4);
            const float sc = SCALE * LOG2E;
            qf[u][c].u.x = pack2(f0.x * sc, f0.y * sc);
            qf[u][c].u.y = pack2(f0.z * sc, f0.w * sc);
            qf[u][c].u.z = pack2(f1.x * sc, f1.y * sc);
            qf[u][c].u.w = pack2(f1.z * sc, f1.w * sc);
        }
    }

    f32x4 acc[2][8] = {};
    float mrun[2] = {-1e30f, -1e30f};
    float lp[2]   = {0.f, 0.f};

    __syncthreads();   // buffer (lo&1) ready (implicit vmcnt(0) drain)

    for (int ch = lo; ch < hi; ++ch){
        const int pb = ch & 1;
        if (ch + 1 < hi) STAGE(ch + 1, pb ^ 1);   // depth-1 prefetch under compute

        const int base = ch * 32;
        const unsigned kb = (unsigned)(pb * 8192);

        // ---------------- QK^T (swapped): st[u][tf] = S^T[t][q] ----------------
        __builtin_amdgcn_s_setprio(1);
        f32x4 st[2][2] = {};
        #pragma unroll
        for (int c = 0; c < 4; ++c){
            #pragma unroll
            for (int tf = 0; tf < 2; ++tf){
                const int trow = tf * 16 + cq;
                const unsigned byte = kb + trow * 256 + ((c * 64 + hh * 16) ^ ((trow & 7) << 4));
                B8 kf; kf.u = *(const uint4*)(lds + byte);
                st[0][tf] = __builtin_amdgcn_mfma_f32_16x16x32_bf16(kf.v, qf[0][c].v, st[0][tf], 0, 0, 0);
                st[1][tf] = __builtin_amdgcn_mfma_f32_16x16x32_bf16(kf.v, qf[1][c].v, st[1][tf], 0, 0, 0);
            }
        }
        __builtin_amdgcn_s_setprio(0);

        // ---------------- softmax (defer-max + deferred-l, base-2) ----------------
        B8 af[2];
        const bool interior = (base + 32 <= vlim);
        #pragma unroll
        for (int u = 0; u < 2; ++u){
            float p[2][4];
            float pm = -1e30f;
            if (interior){
                #pragma unroll
                for (int tf = 0; tf < 2; ++tf){
                    #pragma unroll
                    for (int r = 0; r < 4; ++r){
                        const float s = st[u][tf][r];
                        p[tf][r] = s;
                        pm = fmaxf(pm, s);
                    }
                }
            } else {
                #pragma unroll
                for (int tf = 0; tf < 2; ++tf){
                    #pragma unroll
                    for (int r = 0; r < 4; ++r){
                        const int t = base + tf * 16 + hh * 4 + r;
                        const float s = (t < vlim) ? st[u][tf][r] : -1e30f;
                        p[tf][r] = s;
                        pm = fmaxf(pm, s);
                    }
                }
            }
            pm = fmaxf(pm, __shfl_xor(pm, 16));
            pm = fmaxf(pm, __shfl_xor(pm, 32));

            if (!__all(pm <= mrun[u] + RESCALE_THR)){
                const float mnew  = fmaxf(mrun[u], pm);
                const float alpha = __builtin_amdgcn_exp2f(mrun[u] - mnew);
                mrun[u] = mnew;
                lp[u] *= alpha;
                float a4[4];
                #pragma unroll
                for (int r = 0; r < 4; ++r) a4[r] = __shfl(alpha, hh * 20 + r);
                #pragma unroll
                for (int dc = 0; dc < 8; ++dc){
                    #pragma unroll
                    for (int r = 0; r < 4; ++r) acc[u][dc][r] *= a4[r];
                }
            }
            const float m = mrun[u];
            float rsum = 0.f;
            #pragma unroll
            for (int tf = 0; tf < 2; ++tf){
                #pragma unroll
                for (int r = 0; r < 4; ++r){
                    const float e = __builtin_amdgcn_exp2f(p[tf][r] - m);
                    p[tf][r] = e;
                    rsum += e;
                }
            }
            lp[u] += rsum;

            // k-axis mapping: t(8hh+j) = 16*(j>>2) + 4hh + (j&3)
            af[u].u.x = pack2(p[0][0], p[0][1]);
            af[u].u.y = pack2(p[0][2], p[0][3]);
            af[u].u.z = pack2(p[1][0], p[1][1]);
            af[u].u.w = pack2(p[1][2], p[1][3]);
        }

        // ---------------- PV via hardware transpose reads; vf shared by tiles ----------------
        {
            const unsigned trb = ldsb3 + 16384u + (unsigned)(pb * 8192)
                               + (unsigned)(hh * 128 + cq * 8);
            unsigned long long r0,r1,r2,r3,r4,r5,r6,r7;
            B8 vf;
            __builtin_amdgcn_s_setprio(1);
            // ---- dc=0..3 ----
            TRR(r0, trb, "0");     TRR(r1, trb, "512");
            TRR(r2, trb, "1024");  TRR(r3, trb, "1536");
            TRR(r4, trb, "2048");  TRR(r5, trb, "2560");
            TRR(r6, trb, "3072");  TRR(r7, trb, "3584");
            asm volatile("s_waitcnt lgkmcnt(0)" ::: "memory");
            __builtin_amdgcn_sched_barrier(0);
            vf.u.x=(unsigned)r0; vf.u.y=(unsigned)(r0>>32); vf.u.z=(unsigned)r1; vf.u.w=(unsigned)(r1>>32);
            acc[0][0] = __builtin_amdgcn_mfma_f32_16x16x32_bf16(af[0].v, vf.v, acc[0][0], 0, 0, 0);
            acc[1][0] = __builtin_amdgcn_mfma_f32_16x16x32_bf16(af[1].v, vf.v, acc[1][0], 0, 0, 0);
            vf.u.x=(unsigned)r2; vf.u.y=(unsigned)(r2>>32); vf.u.z=(unsigned)r3; vf.u.w=(unsigned)(r3>>32);
            acc[0][1] = __builtin_amdgcn_mfma_f32_16x16x32_bf16(af[0].v, vf.v, acc[0][1], 0, 0, 0);
            acc[1][1] = __builtin_amdgcn_mfma_f32_16x16x32_bf16(af[1].v, vf.v, acc[1][1], 0, 0, 0);
            vf.u.x=(unsigned)r4; vf.u.y=(unsigned)(r4>>32); vf.u.z=(unsigned)r5; vf.u.w=(unsigned)(r5>>32);
            acc[0][2] = __builtin_amdgcn_mfma_f32_16x16x32_bf16(af[0].v, vf.v, acc[0][2], 0, 0, 0);
            acc[1][2] = __builtin_amdgcn_mfma_f32_16x16x32_bf16(af[1].v, vf.v, acc[1][2], 0, 0, 0);
            vf.u.x=(unsigned)r6; vf.u.y=(unsigned)(r6>>32); vf.u.z=(unsigned)r7; vf.u.w=(unsigned)(r7>>32);
            acc[0][3] = __builtin_amdgcn_mfma_f32_16x16x32_bf16(af[0].v, vf.v, acc[0][3], 0, 0, 0);
            acc[1][3] = __builtin_amdgcn_mfma_f32_16x16x32_bf16(af[1].v, vf.v, acc[1][3], 0, 0, 0);
            // ---- dc=4..7 ----
            TRR(r0, trb, "4096");  TRR(r1, trb, "4608");
            TRR(r2, trb, "5120");  TRR(r3, trb, "5632");
            TRR(r4, trb, "6144");  TRR(r5, trb, "6656");
            TRR(r6, trb, "7168");  TRR(r7, trb, "7680");
            asm volatile("s_waitcnt lgkmcnt(0)" ::: "memory");
            __builtin_amdgcn_sched_barrier(0);
            vf.u.x=(unsigned)r0; vf.u.y=(unsigned)(r0>>32); vf.u.z=(unsigned)r1; vf.u.w=(unsigned)(r1>>32);
            acc[0][4] = __builtin_amdgcn_mfma_f32_16x16x32_bf16(af[0].v, vf.v, acc[0][4], 0, 0, 0);
            acc[1][4] = __builtin_amdgcn_mfma_f32_16x16x32_bf16(af[1].v, vf.v, acc[1][4], 0, 0, 0);
            vf.u.x=(unsigned)r2; vf.u.y=(unsigned)(r2>>32); vf.u.z=(unsigned)r3; vf.u.w=(unsigned)(r3>>32);
            acc[0][5] = __builtin_amdgcn_mfma_f32_16x16x32_bf16(af[0].v, vf.v, acc[0][5], 0, 0, 0);
            acc[1][5] = __builtin_amdgcn_mfma_f32_16x16x32_bf16(af[1].v, vf.v, acc[1][5], 0, 0, 0);
            vf.u.x=(unsigned)r4; vf.u.y=(unsigned)(r4>>32); vf.u.z=(unsigned)r5; vf.u.w=(unsigned)(r5>>32);
            acc[0][6] = __builtin_amdgcn_mfma_f32_16x16x32_bf16(af[0].v, vf.v, acc[0][6], 0, 0, 0);
            acc[1][6] = __builtin_amdgcn_mfma_f32_16x16x32_bf16(af[1].v, vf.v, acc[1][6], 0, 0, 0);
            vf.u.x=(unsigned)r6; vf.u.y=(unsigned)(r6>>32); vf.u.z=(unsigned)r7; vf.u.w=(unsigned)(r7>>32);
            acc[0][7] = __builtin_amdgcn_mfma_f32_16x16x32_bf16(af[0].v, vf.v, acc[0][7], 0, 0, 0);
            acc[1][7] = __builtin_amdgcn_mfma_f32_16x16x32_bf16(af[1].v, vf.v, acc[1][7], 0, 0, 0);
            __builtin_amdgcn_s_setprio(0);
        }
        __syncthreads();   // drains prefetch DMA; separates buf reads from next overwrite
    }

    // ---------------- epilogue ----------------
    if (NSPLIT == 1){
        #pragma unroll
        for (int u = 0; u < 2; ++u){
            float l = lp[u];
            l += __shfl_xor(l, 16);
            l += __shfl_xor(l, 32);
            const float li = 1.0f / l;
            float li4[4];
            #pragma unroll
            for (int r = 0; r < 4; ++r) li4[r] = __shfl(li, hh * 20 + r);
            #pragma unroll
            for (int dc = 0; dc < 8; ++dc){
                #pragma unroll
                for (int r = 0; r < 4; ++r){
                    const int so = s0 + u * 16 + hh * 4 + r;
                    out[(size_t)(b * Q_LEN + so) * (NUM_HEADS * HEAD_DIM) + hq * HEAD_DIM + dc * 16 + cq]
                        = acc[u][dc][r] * li4[r];
                }
            }
        }
    } else {
        // bf16 fragment-order partial: fully coalesced (512B per wave per store)
        unsigned char* pp = part + (size_t)fid * PBYTES;
        #pragma unroll
        for (int u = 0; u < 2; ++u){
            float l = lp[u];
            l += __shfl_xor(l, 16);
            l += __shfl_xor(l, 32);
            if (hh == 0){
                float2 ml; ml.x = mrun[u]; ml.y = l;
                *(float2*)(pp + 32768 + (size_t)(w * 32 + u * 16 + cq) * 8) = ml;
            }
            #pragma unroll
            for (int dc = 0; dc < 8; ++dc){
                uint2 pk;
                pk.x = pack2(acc[u][dc][0], acc[u][dc][1]);
                pk.y = pack2(acc[u][dc][2], acc[u][dc][3]);
                *(uint2*)(pp + (size_t)((((w * 2 + u) * 8 + dc) * 64 + lane)) * 8) = pk;
            }
        }
    }
    #undef STAGE
}

// ============================ merge kernel (coalesced, bf16 partials) ============================
template<int NSPLIT>
__global__ __launch_bounds__(256) void merge_kernel(
    const int* __restrict__ ctxlens,
    const unsigned char* __restrict__ part,
    float* __restrict__ out)
{
    __shared__ float s_w[NSPLIT][128];

    const int item0 = blockIdx.x;
    const int item = (NITEMS - 1) - item0;            // same remap as attn
    const int b   = item & 7;
    const int kvh = (item >> 3) & 7;
    const int s32 = item >> 6;
    const int vlim = ctxlens[b] + (s32 + 1) * 32;
    const int nch  = (vlim + 31) >> 5;

    const int tid = threadIdx.x;

    bool act[NSPLIT];
    #pragma unroll
    for (int s = 0; s < NSPLIT; ++s){
        const int lo = (s * nch) / NSPLIT;
        const int hi = ((s + 1) * nch) / NSPLIT;
        act[s] = hi > lo;
    }

    if (tid < 128){
        float m[NSPLIT], l[NSPLIT];
        float M = -1e30f;
        #pragma unroll
        for (int s = 0; s < NSPLIT; ++s){
            if (act[s]){
                const float2 ml = *(const float2*)(part + (size_t)(item0 * NSPLIT + s) * PBYTES
                                                   + 32768 + (size_t)tid * 8);
                m[s] = ml.x; l[s] = ml.y;
                M = fmaxf(M, m[s]);
            }
        }
        float L = 0.f;
        float wg[NSPLIT];
        #pragma unroll
        for (int s = 0; s < NSPLIT; ++s){
            if (act[s]){
                wg[s] = __builtin_amdgcn_exp2f(m[s] - M);
                L += l[s] * wg[s];
            } else wg[s] = 0.f;
        }
        const float inv = 1.0f / L;
        #pragma unroll
        for (int s = 0; s < NSPLIT; ++s) s_w[s][tid] = wg[s] * inv;
    }
    __syncthreads();

    // O pass: 4096 uint2-slots; uint4 = 2 slots; 2048 uint4 / 256 threads = 8 each.
    // slot S = ((hD*2+u)*8+dc)*64 + ln ; halves: {r0,r1},{r2,r3} of lane ln.
    for (int k = 0; k < 8; ++k){
        const int q4 = tid + k * 256;      // uint4 index
        const int S0 = q4 * 2;             // first slot (ln even)
        const int g  = S0 >> 6;            // (hD*2+u)*8+dc
        const int ln = S0 & 63;
        const int hD = g >> 4;
        const int u  = (g >> 3) & 1;
        const int dc = g & 7;
        const int hh = ln >> 4;
        const int cq = ln & 15;            // even
        const int wbase = hD * 32 + u * 16 + hh * 4;

        float o0[4] = {0.f, 0.f, 0.f, 0.f};   // d = dc*16+cq
        float o1[4] = {0.f, 0.f, 0.f, 0.f};   // d = dc*16+cq+1
        #pragma unroll
        for (int s = 0; s < NSPLIT; ++s){
            if (!act[s]) continue;
            const uint4 v = *(const uint4*)(part + (size_t)(item0 * NSPLIT + s) * PBYTES
                                            + (size_t)q4 * 16);
            const float w0 = s_w[s][wbase + 0];
            const float w1 = s_w[s][wbase + 1];
            const float w2 = s_w[s][wbase + 2];
            const float w3 = s_w[s][wbase + 3];
            o0[0] += w0 * bflo(v.x); o0[1] += w1 * bfhi(v.x);
            o0[2] += w2 * bflo(v.y); o0[3] += w3 * bfhi(v.y);
            o1[0] += w0 * bflo(v.z); o1[1] += w1 * bfhi(v.z);
            o1[2] += w2 * bflo(v.w); o1[3] += w3 * bfhi(v.w);
        }
        float* obase = out + (size_t)(b * Q_LEN + s32 * 32 + u * 16 + hh * 4) * (NUM_HEADS * HEAD_DIM)
                     + (kvh * GQA + hD) * HEAD_DIM + dc * 16 + cq;
        #pragma unroll
        for (int r = 0; r < 4; ++r){
            float2 ov; ov.x = o0[r]; ov.y = o1[r];
            *(float2*)(obase + (size_t)r * (NUM_HEADS * HEAD_DIM)) = ov;
        }
    }
}

extern "C" void kernel_launch(void* const* d_in, const int* in_sizes, int n_in,
                              void* d_out, int out_size, void* d_ws, size_t ws_size,
                              hipStream_t stream) {
    const float* q  = (const float*)d_in[0];
    const float* k  = (const float*)d_in[1];
    const float* v  = (const float*)d_in[2];
    const float* kc = (const float*)d_in[3];
    const float* vc = (const float*)d_in[4];
    const int*   pt = (const int*)d_in[5];
    const int*   cl = (const int*)d_in[6];
    float* o = (float*)d_out;

    const size_t img_bytes = (size_t)64 * KSTREAM;            // 37,748,736 per image
    const size_t off_part  = 256 + 2 * img_bytes;             // 75,497,728
    const size_t need4 = off_part + (size_t)NITEMS * 4 * PBYTES;   // ~144.7 MB
    const size_t need2 = off_part + (size_t)NITEMS * 2 * PBYTES;   // ~110 MB
    const size_t need1 = off_part;

    unsigned char* kimg = (unsigned char*)d_ws + 256;
    unsigned char* vimg = kimg + img_bytes;
    unsigned char* part = (unsigned char*)d_ws + off_part;

    prep_kernel<<<dim3(NCH_MAX, 8, 8), 256, 0, stream>>>(k, v, kc, vc, pt, cl, kimg, vimg);

    if (ws_size >= need4) {
        attn_kernel<4><<<NITEMS * 4, 256, 0, stream>>>(q, cl, o, kimg, vimg, part);
        merge_kernel<4><<<NITEMS, 256, 0, stream>>>(cl, part, o);
    } else if (ws_size >= need2) {
        attn_kernel<2><<<NITEMS * 2, 256, 0, stream>>>(q, cl, o, kimg, vimg, part);
        merge_kernel<2><<<NITEMS, 256, 0, stream>>>(cl, part, o);
    } else if (ws_size >= need1) {
        attn_kernel<1><<<NITEMS, 256, 0, stream>>>(q, cl, o, kimg, vimg, part);
    }
}

// Round 9
// 138.666 us; speedup vs baseline: 2.5521x; 1.3152x over previous
//
#include <hip/hip_runtime.h>
#include <hip/hip_bf16.h>

#define NUM_HEADS   32
#define NUM_KV_HEADS 8
#define HEAD_DIM    128
#define GQA          4
#define Q_LEN      256
#define MAX_PAGES  128
#define PAGE_SIZE   16
#define SCALE 0.08838834764831845f
#define LOG2E 1.44269504088896340736f
#define RESCALE_THR 8.0f

// 64-token chunks (best measured per-chunk economics)
#define NCH_MAX   36                      // ceil((2047+256)/64)
#define CHUNK_B   16384                   // 64 tokens * 128 d * 2B
#define KSTREAM   ((size_t)NCH_MAX * CHUNK_B)
#define NITEMS    512
#define PBYTES    33792                   // 32768 B bf16 O (frag order) + 1024 B ml

typedef __bf16 bf16x8 __attribute__((ext_vector_type(8)));
typedef float  f32x4  __attribute__((ext_vector_type(4)));

union B8 { uint4 u; bf16x8 v; };

__device__ __forceinline__ unsigned f2bf(float x){
    unsigned u = __builtin_bit_cast(unsigned, x);
    return (u + 0x7fffu + ((u >> 16) & 1u)) >> 16;
}
__device__ __forceinline__ unsigned pack2(float lo, float hi){
    return f2bf(lo) | (f2bf(hi) << 16);
}
__device__ __forceinline__ float bflo(unsigned h){
    return __builtin_bit_cast(float, h << 16);
}
__device__ __forceinline__ float bfhi(unsigned h){
    return __builtin_bit_cast(float, h & 0xffff0000u);
}

typedef __attribute__((address_space(3))) unsigned char lds_as3_t;
typedef const __attribute__((address_space(1))) void gas_v;
typedef __attribute__((address_space(3))) void las_v;

#define GLD16(g, l) __builtin_amdgcn_global_load_lds((gas_v*)(g), (las_v*)(l), 16, 0, 0)

#define TRR(dst, base, OFF) asm volatile("ds_read_b64_tr_b16 %0, %1 offset:" OFF \
                                         : "=v"(dst) : "v"(base))

// ============================ pre-pass: gather + bf16 + pre-swizzle (64-t chunks) ============================
__global__ __launch_bounds__(256) void prep_kernel(
    const float* __restrict__ knew,
    const float* __restrict__ vnew,
    const float* __restrict__ kcache,
    const float* __restrict__ vcache,
    const int*   __restrict__ ptab,
    const int*   __restrict__ ctxlens,
    unsigned char* __restrict__ kimg,
    unsigned char* __restrict__ vimg)
{
    const int ch  = blockIdx.x;
    const int kvh = blockIdx.y;
    const int b   = blockIdx.z;
    const int ctxlen = ctxlens[b];
    const int lim = ctxlen + Q_LEN;
    const int base = ch * 64;
    if (base >= lim) return;

    const int tid  = threadIdx.x;
    const int srow = tid >> 2;
    const int seg  = tid & 3;
    const int t    = base + srow;

    unsigned char* kdst = kimg + (size_t)(b * 8 + kvh) * KSTREAM + (size_t)ch * CHUNK_B;
    unsigned char* vdst = vimg + (size_t)(b * 8 + kvh) * KSTREAM + (size_t)ch * CHUNK_B;
    const int swz    = (srow & 7) << 4;
    const int vbyte0 = (srow >> 2) * 128 + (srow & 3) * 32;

    if (t < lim){
        size_t roff;
        const float *ksrc, *vsrc;
        if (t < ctxlen){
            const int page = ptab[b * MAX_PAGES + (t >> 4)];
            roff = ((size_t)(page * PAGE_SIZE + (t & 15)) * NUM_KV_HEADS + kvh) * HEAD_DIM;
            ksrc = kcache + roff; vsrc = vcache + roff;
        } else {
            roff = ((size_t)(b * Q_LEN + (t - ctxlen)) * NUM_KV_HEADS + kvh) * HEAD_DIM;
            ksrc = knew + roff; vsrc = vnew + roff;
        }
        const float* kr = ksrc + seg * 32;
        const float* vr = vsrc + seg * 32;
        #pragma unroll
        for (int i = 0; i < 4; ++i){
            float4 a  = *(const float4*)(kr + i * 8);
            float4 c4 = *(const float4*)(kr + i * 8 + 4);
            uint4 wv;
            wv.x = pack2(a.x, a.y);  wv.y = pack2(a.z, a.w);
            wv.z = pack2(c4.x, c4.y); wv.w = pack2(c4.z, c4.w);
            *(uint4*)(kdst + srow * 256 + ((seg * 64 + i * 16) ^ swz)) = wv;
        }
        #pragma unroll
        for (int db = 0; db < 2; ++db){
            const float4 a0 = *(const float4*)(vr + db * 16 + 0);
            const float4 a1 = *(const float4*)(vr + db * 16 + 4);
            const float4 a2 = *(const float4*)(vr + db * 16 + 8);
            const float4 a3 = *(const float4*)(vr + db * 16 + 12);
            uint4 w0, w1;
            w0.x = pack2(a0.x, a0.y); w0.y = pack2(a0.z, a0.w);
            w0.z = pack2(a1.x, a1.y); w0.w = pack2(a1.z, a1.w);
            w1.x = pack2(a2.x, a2.y); w1.y = pack2(a2.z, a2.w);
            w1.z = pack2(a3.x, a3.y); w1.w = pack2(a3.z, a3.w);
            const int dbk = seg * 2 + db;
            *(uint4*)(vdst + dbk * 2048 + vbyte0)      = w0;
            *(uint4*)(vdst + dbk * 2048 + vbyte0 + 16) = w1;
        }
    } else {
        const uint4 z = {0u, 0u, 0u, 0u};
        #pragma unroll
        for (int i = 0; i < 4; ++i)
            *(uint4*)(kdst + srow * 256 + ((seg * 64 + i * 16) ^ swz)) = z;
        #pragma unroll
        for (int db = 0; db < 2; ++db){
            const int dbk = seg * 2 + db;
            *(uint4*)(vdst + dbk * 2048 + vbyte0)      = z;
            *(uint4*)(vdst + dbk * 2048 + vbyte0 + 16) = z;
        }
    }
}

// ============================ attention kernel (round-5 loop + context-split) ============================
// LDS 64KB: K dbuf [2][16KB] at 0, V dbuf [2][16KB] at 32768. 2 blocks/CU.
template<int NSPLIT>
__global__ __launch_bounds__(256, 2) void attn_kernel(
    const float* __restrict__ q,
    const int*   __restrict__ ctxlens,
    float*       __restrict__ out,
    const unsigned char* __restrict__ kimg,
    const unsigned char* __restrict__ vimg,
    unsigned char* __restrict__ part)
{
    __shared__ __align__(16) unsigned char lds[65536];

    const int tid  = threadIdx.x;
    const int w    = tid >> 6;
    const int lane = tid & 63;
    const int hh   = lane >> 4;
    const int cq   = lane & 15;

    const unsigned ldsb3 = (unsigned)(unsigned long long)(lds_as3_t*)(&lds[0]);

    const int fid   = blockIdx.x;
    const int item0 = fid / NSPLIT;               // 0..511, long items first
    const int seg   = fid % NSPLIT;

    const int b   = item0 & 7;
    const int kvh = (item0 >> 3) & 7;
    const int s32 = 7 - (item0 >> 6);             // s32=7 (longest) dispatched first

    const int s0 = s32 * 32;
    const int ctxlen = ctxlens[b];
    const int vlim = ctxlen + (s32 + 1) * 32;
    const int nch  = (vlim + 63) >> 6;
    const int lo   = (seg * nch) / NSPLIT;
    const int hi   = ((seg + 1) * nch) / NSPLIT;
    if (lo >= hi) return;
    const int hq = kvh * GQA + w;

    const unsigned char* kstream = kimg + (size_t)(b * 8 + kvh) * KSTREAM;
    const unsigned char* vstream = vimg + (size_t)(b * 8 + kvh) * KSTREAM;

    #define STAGE(CH, PB) do { \
        const unsigned char* kg_ = kstream + (size_t)(CH) * CHUNK_B + (w * 4096 + lane * 16); \
        const unsigned char* vg_ = vstream + (size_t)(CH) * CHUNK_B + (w * 4096 + lane * 16); \
        _Pragma("unroll") \
        for (int i_ = 0; i_ < 4; ++i_){ \
            GLD16(kg_ + i_ * 1024, lds + (PB) * CHUNK_B + w * 4096 + i_ * 1024); \
            GLD16(vg_ + i_ * 1024, lds + 32768 + (PB) * CHUNK_B + w * 4096 + i_ * 1024); \
        } \
    } while (0)

    STAGE(lo, lo & 1);

    // Q fragments (B-operand), two 16-row tiles, pre-scaled into log2 domain
    B8 qf[2][4];
    #pragma unroll
    for (int u = 0; u < 2; ++u){
        const float* qrow = q + (size_t)(b * Q_LEN + s0 + u * 16 + cq) * (NUM_HEADS * HEAD_DIM)
                              + hq * HEAD_DIM;
        #pragma unroll
        for (int c = 0; c < 4; ++c){
            const float4 f0 = *(const float4*)(qrow + c * 32 + 8 * hh);
            const float4 f1 = *(const float4*)(qrow + c * 32 + 8 * hh + 4);
            const float sc = SCALE * LOG2E;
            qf[u][c].u.x = pack2(f0.x * sc, f0.y * sc);
            qf[u][c].u.y = pack2(f0.z * sc, f0.w * sc);
            qf[u][c].u.z = pack2(f1.x * sc, f1.y * sc);
            qf[u][c].u.w = pack2(f1.z * sc, f1.w * sc);
        }
    }

    f32x4 acc[2][8] = {};
    float mrun[2] = {-1e30f, -1e30f};
    float lp[2]   = {0.f, 0.f};

    __syncthreads();   // buffer (lo&1) ready (implicit vmcnt(0) drain)

    for (int ch = lo; ch < hi; ++ch){
        const int pb = ch & 1;
        if (ch + 1 < hi) STAGE(ch + 1, pb ^ 1);

        const int base = ch * 64;
        const unsigned kb = (unsigned)(pb * CHUNK_B);

        // ---------------- QK^T (swapped): st[u][tf] = S^T[t][q] ----------------
        __builtin_amdgcn_s_setprio(1);
        f32x4 st[2][4] = {};
        #pragma unroll
        for (int c = 0; c < 4; ++c){
            #pragma unroll
            for (int tf = 0; tf < 4; ++tf){
                const int trow = tf * 16 + cq;
                const unsigned byte = kb + trow * 256 + ((c * 64 + hh * 16) ^ ((trow & 7) << 4));
                B8 kf; kf.u = *(const uint4*)(lds + byte);
                st[0][tf] = __builtin_amdgcn_mfma_f32_16x16x32_bf16(kf.v, qf[0][c].v, st[0][tf], 0, 0, 0);
                st[1][tf] = __builtin_amdgcn_mfma_f32_16x16x32_bf16(kf.v, qf[1][c].v, st[1][tf], 0, 0, 0);
            }
        }
        __builtin_amdgcn_s_setprio(0);

        // ---------------- softmax (defer-max + deferred-l, base-2) ----------------
        B8 af[2][2];
        const bool interior = (base + 64 <= vlim);
        #pragma unroll
        for (int u = 0; u < 2; ++u){
            float p[4][4];
            float pm = -1e30f;
            if (interior){
                #pragma unroll
                for (int tf = 0; tf < 4; ++tf){
                    #pragma unroll
                    for (int r = 0; r < 4; ++r){
                        const float s = st[u][tf][r];
                        p[tf][r] = s;
                        pm = fmaxf(pm, s);
                    }
                }
            } else {
                #pragma unroll
                for (int tf = 0; tf < 4; ++tf){
                    #pragma unroll
                    for (int r = 0; r < 4; ++r){
                        const int t = base + tf * 16 + hh * 4 + r;
                        const float s = (t < vlim) ? st[u][tf][r] : -1e30f;
                        p[tf][r] = s;
                        pm = fmaxf(pm, s);
                    }
                }
            }
            pm = fmaxf(pm, __shfl_xor(pm, 16));
            pm = fmaxf(pm, __shfl_xor(pm, 32));

            if (!__all(pm <= mrun[u] + RESCALE_THR)){
                const float mnew  = fmaxf(mrun[u], pm);
                const float alpha = __builtin_amdgcn_exp2f(mrun[u] - mnew);
                mrun[u] = mnew;
                lp[u] *= alpha;
                float a4[4];
                #pragma unroll
                for (int r = 0; r < 4; ++r) a4[r] = __shfl(alpha, hh * 20 + r);
                #pragma unroll
                for (int dc = 0; dc < 8; ++dc){
                    #pragma unroll
                    for (int r = 0; r < 4; ++r) acc[u][dc][r] *= a4[r];
                }
            }
            const float m = mrun[u];
            float rsum = 0.f;
            #pragma unroll
            for (int tf = 0; tf < 4; ++tf){
                #pragma unroll
                for (int r = 0; r < 4; ++r){
                    const float e = __builtin_amdgcn_exp2f(p[tf][r] - m);
                    p[tf][r] = e;
                    rsum += e;
                }
            }
            lp[u] += rsum;

            // k-axis mapping: t(kk, 8hh+j) = 32kk + 16*(j>>2) + 4hh + (j&3)
            unsigned pk01[4], pk23[4];
            #pragma unroll
            for (int tf = 0; tf < 4; ++tf){
                pk01[tf] = pack2(p[tf][0], p[tf][1]);
                pk23[tf] = pack2(p[tf][2], p[tf][3]);
            }
            af[u][0].u.x = pk01[0]; af[u][0].u.y = pk23[0]; af[u][0].u.z = pk01[1]; af[u][0].u.w = pk23[1];
            af[u][1].u.x = pk01[2]; af[u][1].u.y = pk23[2]; af[u][1].u.z = pk01[3]; af[u][1].u.w = pk23[3];
        }

        // ---------------- PV via hardware transpose reads; vf shared by tiles ----------------
        {
            const unsigned trb = ldsb3 + 32768u + (unsigned)(pb * CHUNK_B) + (unsigned)(hh * 128 + cq * 8);
            unsigned long long r0,r1,r2,r3,r4,r5,r6,r7;
            B8 vf;
            __builtin_amdgcn_s_setprio(1);
            // ---- kk=0, dc=0..3 ----
            TRR(r0, trb, "0");     TRR(r1, trb, "512");
            TRR(r2, trb, "2048");  TRR(r3, trb, "2560");
            TRR(r4, trb, "4096");  TRR(r5, trb, "4608");
            TRR(r6, trb, "6144");  TRR(r7, trb, "6656");
            asm volatile("s_waitcnt lgkmcnt(0)" ::: "memory");
            __builtin_amdgcn_sched_barrier(0);
            vf.u.x=(unsigned)r0; vf.u.y=(unsigned)(r0>>32); vf.u.z=(unsigned)r1; vf.u.w=(unsigned)(r1>>32);
            acc[0][0] = __builtin_amdgcn_mfma_f32_16x16x32_bf16(af[0][0].v, vf.v, acc[0][0], 0, 0, 0);
            acc[1][0] = __builtin_amdgcn_mfma_f32_16x16x32_bf16(af[1][0].v, vf.v, acc[1][0], 0, 0, 0);
            vf.u.x=(unsigned)r2; vf.u.y=(unsigned)(r2>>32); vf.u.z=(unsigned)r3; vf.u.w=(unsigned)(r3>>32);
            acc[0][1] = __builtin_amdgcn_mfma_f32_16x16x32_bf16(af[0][0].v, vf.v, acc[0][1], 0, 0, 0);
            acc[1][1] = __builtin_amdgcn_mfma_f32_16x16x32_bf16(af[1][0].v, vf.v, acc[1][1], 0, 0, 0);
            vf.u.x=(unsigned)r4; vf.u.y=(unsigned)(r4>>32); vf.u.z=(unsigned)r5; vf.u.w=(unsigned)(r5>>32);
            acc[0][2] = __builtin_amdgcn_mfma_f32_16x16x32_bf16(af[0][0].v, vf.v, acc[0][2], 0, 0, 0);
            acc[1][2] = __builtin_amdgcn_mfma_f32_16x16x32_bf16(af[1][0].v, vf.v, acc[1][2], 0, 0, 0);
            vf.u.x=(unsigned)r6; vf.u.y=(unsigned)(r6>>32); vf.u.z=(unsigned)r7; vf.u.w=(unsigned)(r7>>32);
            acc[0][3] = __builtin_amdgcn_mfma_f32_16x16x32_bf16(af[0][0].v, vf.v, acc[0][3], 0, 0, 0);
            acc[1][3] = __builtin_amdgcn_mfma_f32_16x16x32_bf16(af[1][0].v, vf.v, acc[1][3], 0, 0, 0);
            // ---- kk=0, dc=4..7 ----
            TRR(r0, trb, "8192");  TRR(r1, trb, "8704");
            TRR(r2, trb, "10240"); TRR(r3, trb, "10752");
            TRR(r4, trb, "12288"); TRR(r5, trb, "12800");
            TRR(r6, trb, "14336"); TRR(r7, trb, "14848");
            asm volatile("s_waitcnt lgkmcnt(0)" ::: "memory");
            __builtin_amdgcn_sched_barrier(0);
            vf.u.x=(unsigned)r0; vf.u.y=(unsigned)(r0>>32); vf.u.z=(unsigned)r1; vf.u.w=(unsigned)(r1>>32);
            acc[0][4] = __builtin_amdgcn_mfma_f32_16x16x32_bf16(af[0][0].v, vf.v, acc[0][4], 0, 0, 0);
            acc[1][4] = __builtin_amdgcn_mfma_f32_16x16x32_bf16(af[1][0].v, vf.v, acc[1][4], 0, 0, 0);
            vf.u.x=(unsigned)r2; vf.u.y=(unsigned)(r2>>32); vf.u.z=(unsigned)r3; vf.u.w=(unsigned)(r3>>32);
            acc[0][5] = __builtin_amdgcn_mfma_f32_16x16x32_bf16(af[0][0].v, vf.v, acc[0][5], 0, 0, 0);
            acc[1][5] = __builtin_amdgcn_mfma_f32_16x16x32_bf16(af[1][0].v, vf.v, acc[1][5], 0, 0, 0);
            vf.u.x=(unsigned)r4; vf.u.y=(unsigned)(r4>>32); vf.u.z=(unsigned)r5; vf.u.w=(unsigned)(r5>>32);
            acc[0][6] = __builtin_amdgcn_mfma_f32_16x16x32_bf16(af[0][0].v, vf.v, acc[0][6], 0, 0, 0);
            acc[1][6] = __builtin_amdgcn_mfma_f32_16x16x32_bf16(af[1][0].v, vf.v, acc[1][6], 0, 0, 0);
            vf.u.x=(unsigned)r6; vf.u.y=(unsigned)(r6>>32); vf.u.z=(unsigned)r7; vf.u.w=(unsigned)(r7>>32);
            acc[0][7] = __builtin_amdgcn_mfma_f32_16x16x32_bf16(af[0][0].v, vf.v, acc[0][7], 0, 0, 0);
            acc[1][7] = __builtin_amdgcn_mfma_f32_16x16x32_bf16(af[1][0].v, vf.v, acc[1][7], 0, 0, 0);
            // ---- kk=1, dc=0..3 ----
            TRR(r0, trb, "1024");  TRR(r1, trb, "1536");
            TRR(r2, trb, "3072");  TRR(r3, trb, "3584");
            TRR(r4, trb, "5120");  TRR(r5, trb, "5632");
            TRR(r6, trb, "7168");  TRR(r7, trb, "7680");
            asm volatile("s_waitcnt lgkmcnt(0)" ::: "memory");
            __builtin_amdgcn_sched_barrier(0);
            vf.u.x=(unsigned)r0; vf.u.y=(unsigned)(r0>>32); vf.u.z=(unsigned)r1; vf.u.w=(unsigned)(r1>>32);
            acc[0][0] = __builtin_amdgcn_mfma_f32_16x16x32_bf16(af[0][1].v, vf.v, acc[0][0], 0, 0, 0);
            acc[1][0] = __builtin_amdgcn_mfma_f32_16x16x32_bf16(af[1][1].v, vf.v, acc[1][0], 0, 0, 0);
            vf.u.x=(unsigned)r2; vf.u.y=(unsigned)(r2>>32); vf.u.z=(unsigned)r3; vf.u.w=(unsigned)(r3>>32);
            acc[0][1] = __builtin_amdgcn_mfma_f32_16x16x32_bf16(af[0][1].v, vf.v, acc[0][1], 0, 0, 0);
            acc[1][1] = __builtin_amdgcn_mfma_f32_16x16x32_bf16(af[1][1].v, vf.v, acc[1][1], 0, 0, 0);
            vf.u.x=(unsigned)r4; vf.u.y=(unsigned)(r4>>32); vf.u.z=(unsigned)r5; vf.u.w=(unsigned)(r5>>32);
            acc[0][2] = __builtin_amdgcn_mfma_f32_16x16x32_bf16(af[0][1].v, vf.v, acc[0][2], 0, 0, 0);
            acc[1][2] = __builtin_amdgcn_mfma_f32_16x16x32_bf16(af[1][1].v, vf.v, acc[1][2], 0, 0, 0);
            vf.u.x=(unsigned)r6; vf.u.y=(unsigned)(r6>>32); vf.u.z=(unsigned)r7; vf.u.w=(unsigned)(r7>>32);
            acc[0][3] = __builtin_amdgcn_mfma_f32_16x16x32_bf16(af[0][1].v, vf.v, acc[0][3], 0, 0, 0);
            acc[1][3] = __builtin_amdgcn_mfma_f32_16x16x32_bf16(af[1][1].v, vf.v, acc[1][3], 0, 0, 0);
            // ---- kk=1, dc=4..7 ----
            TRR(r0, trb, "9216");  TRR(r1, trb, "9728");
            TRR(r2, trb, "11264"); TRR(r3, trb, "11776");
            TRR(r4, trb, "13312"); TRR(r5, trb, "13824");
            TRR(r6, trb, "15360"); TRR(r7, trb, "15872");
            asm volatile("s_waitcnt lgkmcnt(0)" ::: "memory");
            __builtin_amdgcn_sched_barrier(0);
            vf.u.x=(unsigned)r0; vf.u.y=(unsigned)(r0>>32); vf.u.z=(unsigned)r1; vf.u.w=(unsigned)(r1>>32);
            acc[0][4] = __builtin_amdgcn_mfma_f32_16x16x32_bf16(af[0][1].v, vf.v, acc[0][4], 0, 0, 0);
            acc[1][4] = __builtin_amdgcn_mfma_f32_16x16x32_bf16(af[1][1].v, vf.v, acc[1][4], 0, 0, 0);
            vf.u.x=(unsigned)r2; vf.u.y=(unsigned)(r2>>32); vf.u.z=(unsigned)r3; vf.u.w=(unsigned)(r3>>32);
            acc[0][5] = __builtin_amdgcn_mfma_f32_16x16x32_bf16(af[0][1].v, vf.v, acc[0][5], 0, 0, 0);
            acc[1][5] = __builtin_amdgcn_mfma_f32_16x16x32_bf16(af[1][1].v, vf.v, acc[1][5], 0, 0, 0);
            vf.u.x=(unsigned)r4; vf.u.y=(unsigned)(r4>>32); vf.u.z=(unsigned)r5; vf.u.w=(unsigned)(r5>>32);
            acc[0][6] = __builtin_amdgcn_mfma_f32_16x16x32_bf16(af[0][1].v, vf.v, acc[0][6], 0, 0, 0);
            acc[1][6] = __builtin_amdgcn_mfma_f32_16x16x32_bf16(af[1][1].v, vf.v, acc[1][6], 0, 0, 0);
            vf.u.x=(unsigned)r6; vf.u.y=(unsigned)(r6>>32); vf.u.z=(unsigned)r7; vf.u.w=(unsigned)(r7>>32);
            acc[0][7] = __builtin_amdgcn_mfma_f32_16x16x32_bf16(af[0][1].v, vf.v, acc[0][7], 0, 0, 0);
            acc[1][7] = __builtin_amdgcn_mfma_f32_16x16x32_bf16(af[1][1].v, vf.v, acc[1][7], 0, 0, 0);
            __builtin_amdgcn_s_setprio(0);
        }
        __syncthreads();
    }

    // ---------------- epilogue ----------------
    if (NSPLIT == 1){
        #pragma unroll
        for (int u = 0; u < 2; ++u){
            float l = lp[u];
            l += __shfl_xor(l, 16);
            l += __shfl_xor(l, 32);
            const float li = 1.0f / l;
            float li4[4];
            #pragma unroll
            for (int r = 0; r < 4; ++r) li4[r] = __shfl(li, hh * 20 + r);
            #pragma unroll
            for (int dc = 0; dc < 8; ++dc){
                #pragma unroll
                for (int r = 0; r < 4; ++r){
                    const int so = s0 + u * 16 + hh * 4 + r;
                    out[(size_t)(b * Q_LEN + so) * (NUM_HEADS * HEAD_DIM) + hq * HEAD_DIM + dc * 16 + cq]
                        = acc[u][dc][r] * li4[r];
                }
            }
        }
    } else {
        // bf16 fragment-order partial: fully coalesced
        unsigned char* pp = part + (size_t)fid * PBYTES;
        #pragma unroll
        for (int u = 0; u < 2; ++u){
            float l = lp[u];
            l += __shfl_xor(l, 16);
            l += __shfl_xor(l, 32);
            if (hh == 0){
                float2 ml; ml.x = mrun[u]; ml.y = l;
                *(float2*)(pp + 32768 + (size_t)(w * 32 + u * 16 + cq) * 8) = ml;
            }
            #pragma unroll
            for (int dc = 0; dc < 8; ++dc){
                uint2 pk;
                pk.x = pack2(acc[u][dc][0], acc[u][dc][1]);
                pk.y = pack2(acc[u][dc][2], acc[u][dc][3]);
                *(uint2*)(pp + (size_t)((((w * 2 + u) * 8 + dc) * 64 + lane)) * 8) = pk;
            }
        }
    }
    #undef STAGE
}

// ============================ merge kernel (coalesced, bf16 partials) ============================
template<int NSPLIT>
__global__ __launch_bounds__(256) void merge_kernel(
    const int* __restrict__ ctxlens,
    const unsigned char* __restrict__ part,
    float* __restrict__ out)
{
    __shared__ float s_w[NSPLIT][128];

    const int item0 = blockIdx.x;
    const int b   = item0 & 7;
    const int kvh = (item0 >> 3) & 7;
    const int s32 = 7 - (item0 >> 6);
    const int vlim = ctxlens[b] + (s32 + 1) * 32;
    const int nch  = (vlim + 63) >> 6;

    const int tid = threadIdx.x;

    bool act[NSPLIT];
    #pragma unroll
    for (int s = 0; s < NSPLIT; ++s){
        const int lo = (s * nch) / NSPLIT;
        const int hi = ((s + 1) * nch) / NSPLIT;
        act[s] = hi > lo;
    }

    if (tid < 128){
        float m[NSPLIT], l[NSPLIT];
        float M = -1e30f;
        #pragma unroll
        for (int s = 0; s < NSPLIT; ++s){
            if (act[s]){
                const float2 ml = *(const float2*)(part + (size_t)(item0 * NSPLIT + s) * PBYTES
                                                   + 32768 + (size_t)tid * 8);
                m[s] = ml.x; l[s] = ml.y;
                M = fmaxf(M, m[s]);
            }
        }
        float L = 0.f;
        float wg[NSPLIT];
        #pragma unroll
        for (int s = 0; s < NSPLIT; ++s){
            if (act[s]){
                wg[s] = __builtin_amdgcn_exp2f(m[s] - M);
                L += l[s] * wg[s];
            } else wg[s] = 0.f;
        }
        const float inv = 1.0f / L;
        #pragma unroll
        for (int s = 0; s < NSPLIT; ++s) s_w[s][tid] = wg[s] * inv;
    }
    __syncthreads();

    // O pass: 4096 uint2-slots; uint4 = 2 slots; 2048 uint4 / 256 threads = 8 each.
    for (int k = 0; k < 8; ++k){
        const int q4 = tid + k * 256;
        const int S0 = q4 * 2;
        const int g  = S0 >> 6;
        const int ln = S0 & 63;
        const int hD = g >> 4;
        const int u  = (g >> 3) & 1;
        const int dc = g & 7;
        const int hh = ln >> 4;
        const int cq = ln & 15;
        const int wbase = hD * 32 + u * 16 + hh * 4;

        float o0[4] = {0.f, 0.f, 0.f, 0.f};
        float o1[4] = {0.f, 0.f, 0.f, 0.f};
        #pragma unroll
        for (int s = 0; s < NSPLIT; ++s){
            if (!act[s]) continue;
            const uint4 v = *(const uint4*)(part + (size_t)(item0 * NSPLIT + s) * PBYTES
                                            + (size_t)q4 * 16);
            const float w0 = s_w[s][wbase + 0];
            const float w1 = s_w[s][wbase + 1];
            const float w2 = s_w[s][wbase + 2];
            const float w3 = s_w[s][wbase + 3];
            o0[0] += w0 * bflo(v.x); o0[1] += w1 * bfhi(v.x);
            o0[2] += w2 * bflo(v.y); o0[3] += w3 * bfhi(v.y);
            o1[0] += w0 * bflo(v.z); o1[1] += w1 * bfhi(v.z);
            o1[2] += w2 * bflo(v.w); o1[3] += w3 * bfhi(v.w);
        }
        float* obase = out + (size_t)(b * Q_LEN + s32 * 32 + u * 16 + hh * 4) * (NUM_HEADS * HEAD_DIM)
                     + (kvh * GQA + hD) * HEAD_DIM + dc * 16 + cq;
        #pragma unroll
        for (int r = 0; r < 4; ++r){
            float2 ov; ov.x = o0[r]; ov.y = o1[r];
            *(float2*)(obase + (size_t)r * (NUM_HEADS * HEAD_DIM)) = ov;
        }
    }
}

extern "C" void kernel_launch(void* const* d_in, const int* in_sizes, int n_in,
                              void* d_out, int out_size, void* d_ws, size_t ws_size,
                              hipStream_t stream) {
    const float* q  = (const float*)d_in[0];
    const float* k  = (const float*)d_in[1];
    const float* v  = (const float*)d_in[2];
    const float* kc = (const float*)d_in[3];
    const float* vc = (const float*)d_in[4];
    const int*   pt = (const int*)d_in[5];
    const int*   cl = (const int*)d_in[6];
    float* o = (float*)d_out;

    const size_t img_bytes = (size_t)64 * KSTREAM;            // 37,748,736 per image
    const size_t off_part  = 256 + 2 * img_bytes;             // 75,497,728
    const size_t need2 = off_part + (size_t)NITEMS * 2 * PBYTES;   // ~110 MB
    const size_t need1 = off_part;

    unsigned char* kimg = (unsigned char*)d_ws + 256;
    unsigned char* vimg = kimg + img_bytes;
    unsigned char* part = (unsigned char*)d_ws + off_part;

    prep_kernel<<<dim3(NCH_MAX, 8, 8), 256, 0, stream>>>(k, v, kc, vc, pt, cl, kimg, vimg);

    if (ws_size >= need2) {
        attn_kernel<2><<<NITEMS * 2, 256, 0, stream>>>(q, cl, o, kimg, vimg, part);
        merge_kernel<2><<<NITEMS, 256, 0, stream>>>(cl, part, o);
    } else if (ws_size >= need1) {
        attn_kernel<1><<<NITEMS, 256, 0, stream>>>(q, cl, o, kimg, vimg, part);
    }
}